// Round 6
// baseline (103.755 us; speedup 1.0000x reference)
//
#include <hip/hip_runtime.h>
#include <math.h>

#define N_TOTAL 8192
#define BHALF   4096
#define KDIM    128
#define NTILES  64                            // 8192 / 128
#define NBLK    (NTILES * (NTILES + 1) / 2)   // 2080 triangular tiles

typedef __bf16 bf16x8 __attribute__((ext_vector_type(8)));
typedef __bf16 bf16x2 __attribute__((ext_vector_type(2)));
typedef float  f32x4  __attribute__((ext_vector_type(4)));

// ---------------------------------------------------------------------------
// Kernel A (fused prep+pos): one wave per pair (i, i+BHALF).
//  fp32 sq-norms (exact), bf16 copy of both rows, zero T,
//  per-block positive-pair partial -> posPart[block] (plain store).
// ---------------------------------------------------------------------------
__global__ __launch_bounds__(256) void k_prep_pos(const float* __restrict__ F,
                                                  __bf16* __restrict__ Fbf,
                                                  float* __restrict__ sq,
                                                  float* __restrict__ T,
                                                  float* __restrict__ posPart) {
    int t = threadIdx.x;
    int w = t >> 6, l = t & 63;
    int p = blockIdx.x * 4 + w;          // pair index 0..4095
    const float2* r1 = (const float2*)(F + (size_t)p * KDIM);
    const float2* r2 = (const float2*)(F + (size_t)(p + BHALF) * KDIM);
    float2 a = r1[l];
    float2 c = r2[l];

    float s1 = fmaf(a.x, a.x, a.y * a.y);
    float s2 = fmaf(c.x, c.x, c.y * c.y);
    float dp = fmaf(a.x, c.x, a.y * c.y);
#pragma unroll
    for (int off = 32; off > 0; off >>= 1) {
        s1 += __shfl_down(s1, off);
        s2 += __shfl_down(s2, off);
        dp += __shfl_down(dp, off);
    }

    bf16x2 pa, pc;
    pa[0] = (__bf16)a.x; pa[1] = (__bf16)a.y;
    pc[0] = (__bf16)c.x; pc[1] = (__bf16)c.y;
    ((bf16x2*)(Fbf + (size_t)p * KDIM))[l] = pa;
    ((bf16x2*)(Fbf + (size_t)(p + BHALF) * KDIM))[l] = pc;

    __shared__ float posRed[4];
    if (l == 0) {
        sq[p] = s1;
        sq[p + BHALF] = s2;
        T[p] = 0.0f;
        T[p + BHALF] = 0.0f;
        float d2 = fmaxf(s1 + s2 - 2.0f * dp, 0.0f);
        posRed[w] = logf(1.0f + d2);
    }
    __syncthreads();
    if (t == 0)
        posPart[blockIdx.x] = posRed[0] + posRed[1] + posRed[2] + posRed[3];
}

// ---------------------------------------------------------------------------
// Kernel B: MFMA pairwise Cauchy row/col sums — NO LDS STAGING.
// Fbf (2 MB) is L2-resident; each wave loads its 16x16x32 fragments straight
// from global into registers. Fragment load = 16 rows x 64 contiguous bytes
// (kb-quads cover granules 4s..4s+3) -> 16 fully-used 64B lines per load.
// 2080 triangular 128x128 tiles; 4 waves (2x2), 4x4 frags each; no barriers
// until the 2-KB epilogue scratch. Occupancy VGPR-bound (~12 waves/CU), all
// waves independent -> L2 latency hidden by TLP, no vmcnt(0) drains.
// Strict-upper mask on diagonal tiles; T excludes diagonal (final: log(T)).
// ---------------------------------------------------------------------------
__global__ __launch_bounds__(256, 3) void k_pairwise(
        const __bf16* __restrict__ Fbf,
        const float* __restrict__ sq,
        float* __restrict__ T) {
    // triangular decode: block b -> (ti, tj), tj >= ti
    int b = blockIdx.x;
    int ti = (int)floorf((129.0f - sqrtf(16641.0f - 8.0f * (float)b)) * 0.5f);
    while (ti * (129 - ti) / 2 > b) --ti;
    while ((ti + 1) * (128 - ti) / 2 <= b) ++ti;
    int tj = ti + (b - ti * (129 - ti) / 2);
    int I = ti * 128, J = tj * 128;
    bool diag = (ti == tj);

    __shared__ float rowAcc[128][2];
    __shared__ float colAcc[128][2];

    int t = threadIdx.x;
    int w = t >> 6;               // wave 0..3
    int l = t & 63;
    int wr = w >> 1, wc = w & 1;  // 2x2 wave grid, 64x64 quadrant each
    int low = l & 15, kb = l >> 4;

    const bf16x8* Fg = (const bf16x8*)Fbf;   // granule-indexed: row*16 + g

    // ---- K-loop: 4 steps of K=32, fragments straight from L2 ----
    f32x4 acc[4][4] = {};
#pragma unroll
    for (int s = 0; s < 4; ++s) {
        int g = s * 4 + kb;
        bf16x8 aF[4], bF[4];
#pragma unroll
        for (int fr = 0; fr < 4; ++fr)
            aF[fr] = Fg[(size_t)(I + wr * 64 + fr * 16 + low) * 16 + g];
#pragma unroll
        for (int fc = 0; fc < 4; ++fc)
            bF[fc] = Fg[(size_t)(J + wc * 64 + fc * 16 + low) * 16 + g];
#pragma unroll
        for (int fr = 0; fr < 4; ++fr)
#pragma unroll
            for (int fc = 0; fc < 4; ++fc)
                acc[fr][fc] = __builtin_amdgcn_mfma_f32_16x16x32_bf16(
                    aF[fr], bF[fc], acc[fr][fc], 0, 0, 0);
    }

    // ---- epilogue: Cauchy + row/col partial sums ----
    // C/D layout: col = low, row = kb*4 + reg (within each 16x16 fragment)
    float sqi[4][4], sqj[4];
#pragma unroll
    for (int fr = 0; fr < 4; ++fr)
#pragma unroll
        for (int r = 0; r < 4; ++r)
            sqi[fr][r] = sq[I + wr * 64 + fr * 16 + kb * 4 + r];
#pragma unroll
    for (int fc = 0; fc < 4; ++fc)
        sqj[fc] = sq[J + wc * 64 + fc * 16 + low];

    float rowPart[4][4] = {};
    float colPart[4] = {0.f, 0.f, 0.f, 0.f};
#define EPI(MASK)                                                              \
    _Pragma("unroll")                                                          \
    for (int fr = 0; fr < 4; ++fr) {                                           \
        _Pragma("unroll")                                                      \
        for (int fc = 0; fc < 4; ++fc) {                                       \
            _Pragma("unroll")                                                  \
            for (int r = 0; r < 4; ++r) {                                      \
                float d2 = sqi[fr][r] + sqj[fc] - 2.0f * acc[fr][fc][r];       \
                d2 = fmaxf(d2, 0.0f);                                          \
                float v = __builtin_amdgcn_rcpf(1.0f + d2);                    \
                if (MASK) {                                                    \
                    int R = wr * 64 + fr * 16 + kb * 4 + r;                    \
                    int C = wc * 64 + fc * 16 + low;                           \
                    v = (C > R) ? v : 0.0f;   /* strict upper on diag tile */  \
                }                                                              \
                rowPart[fr][r] += v;                                           \
                colPart[fc] += v;                                              \
            }                                                                  \
        }                                                                      \
    }
    if (diag) { EPI(true) } else { EPI(false) }
#undef EPI

    // row partials: reduce across the 16 lanes sharing a row (low)
#pragma unroll
    for (int fr = 0; fr < 4; ++fr)
#pragma unroll
        for (int r = 0; r < 4; ++r) {
            float x = rowPart[fr][r];
            x += __shfl_xor(x, 1);
            x += __shfl_xor(x, 2);
            x += __shfl_xor(x, 4);
            x += __shfl_xor(x, 8);
            if (low == 0)
                rowAcc[wr * 64 + fr * 16 + kb * 4 + r][wc] = x;
        }

    // col partials: reduce across the 4 lane-quads (kb)
#pragma unroll
    for (int fc = 0; fc < 4; ++fc) {
        float x = colPart[fc];
        x += __shfl_xor(x, 16);
        x += __shfl_xor(x, 32);
        if (kb == 0)
            colAcc[wc * 64 + fc * 16 + low][wr] = x;
    }
    __syncthreads();

    // scatter: every tile adds both row sums (T[I+...]) and col sums (T[J+...])
    if (t < 128) {
        atomicAdd(&T[I + t], rowAcc[t][0] + rowAcc[t][1]);
    } else {
        int c = t - 128;
        atomicAdd(&T[J + c], colAcc[c][0] + colAcc[c][1]);
    }
}

// ---------------------------------------------------------------------------
// Kernel C: final scalar, single block.
// T excludes the diagonal -> neg term = mean log(T); loss = S_T/(2b)+S_pos/b.
// ---------------------------------------------------------------------------
__global__ __launch_bounds__(512) void k_final(const float* __restrict__ T,
                                               const float* __restrict__ posPart,
                                               float* __restrict__ out) {
    int t = threadIdx.x;
    float s = 0.0f;
    for (int i = t; i < N_TOTAL; i += 512) s += logf(T[i]);
    s *= 0.5f;
    for (int i = t; i < 1024; i += 512) s += posPart[i];
#pragma unroll
    for (int off = 32; off > 0; off >>= 1) s += __shfl_down(s, off);
    __shared__ float red[8];
    int w = t >> 6, l = t & 63;
    if (l == 0) red[w] = s;
    __syncthreads();
    if (t == 0) {
        float S = 0.0f;
#pragma unroll
        for (int i = 0; i < 8; ++i) S += red[i];
        out[0] = S / (float)BHALF;
    }
}

// ---------------------------------------------------------------------------
extern "C" void kernel_launch(void* const* d_in, const int* in_sizes, int n_in,
                              void* d_out, int out_size, void* d_ws, size_t ws_size,
                              hipStream_t stream) {
    const float* F = (const float*)d_in[0];
    float* out = (float*)d_out;

    char* ws = (char*)d_ws;
    __bf16* Fbf     = (__bf16*)ws;                               // 2 MB
    float*  sq      = (float*)(ws + (size_t)N_TOTAL * KDIM * 2); // 8192 f
    float*  T       = sq + N_TOTAL;                              // 8192 f
    float*  posPart = T + N_TOTAL;                               // 1024 f

    k_prep_pos<<<BHALF / 4, 256, 0, stream>>>(F, Fbf, sq, T, posPart);
    k_pairwise<<<NBLK, 256, 0, stream>>>(Fbf, sq, T);
    k_final<<<1, 512, 0, stream>>>(T, posPart, out);
}